// Round 1
// baseline (255.477 us; speedup 1.0000x reference)
//
#include <hip/hip_runtime.h>
#include <stdint.h>

#define H 256
#define BT 4096
#define TS 128
#define NSLOTS 64
#define ROWS 16
#define NBLK 256
#define NTH 512

typedef __attribute__((ext_vector_type(8))) short bf16x8;
typedef __attribute__((ext_vector_type(4))) float f32x4;
typedef __attribute__((ext_vector_type(8))) unsigned short u16x8;

__device__ __forceinline__ float exp2_fast(float x){ float r; asm("v_exp_f32 %0, %1" : "=v"(r) : "v"(x)); return r; }
__device__ __forceinline__ float rcp_fast(float x){ float r; asm("v_rcp_f32 %0, %1" : "=v"(r) : "v"(x)); return r; }
__device__ __forceinline__ float rsq_fast(float x){ float r; asm("v_rsq_f32 %0, %1" : "=v"(r) : "v"(x)); return r; }
__device__ __forceinline__ float tanh_fast(float x){
  // tanh(x) = 1 - 2/(2^(2*log2e*x)+1); saturates correctly at +-inf args
  float e = exp2_fast(x * 2.8853900817779268f);
  return 1.0f - 2.0f * rcp_fast(e + 1.0f);
}
__device__ __forceinline__ unsigned short bf16_rne(float f){
  unsigned u = __float_as_uint(f);
  u += 0x7fffu + ((u >> 16) & 1u);
  return (unsigned short)(u >> 16);
}
__device__ __forceinline__ float bf16f(unsigned short h){ return __uint_as_float(((unsigned)h) << 16); }

__global__ __launch_bounds__(NTH, 2) void wp_kernel(
    const float* __restrict__ x, const float* __restrict__ We, const float* __restrict__ be,
    const float* __restrict__ Wu, const float* __restrict__ bu, const float* __restrict__ gm,
    const float* __restrict__ bt, const float* __restrict__ Wo, const float* __restrict__ bo,
    const float* __restrict__ cst, unsigned short* __restrict__ hist, float* __restrict__ out,
    int use_hist)
{
  // padded leading dims (260/132) keep LDS bank conflicts <=2-way (free)
  __shared__ __align__(16) float emb[10][260];
  __shared__ __align__(16) float hcur[ROWS][260];
  __shared__ __align__(16) float hpre[ROWS][260];
  __shared__ __align__(16) unsigned short afrag[8][64][8]; // [kc][lane][elem], linear per wave
  __shared__ unsigned char xidx[ROWS][132];
  __shared__ float bu_s[H], gm_s[H], bt_s[H];

  const int tid = threadIdx.x;
  const int bid = blockIdx.x;
  const int r0 = bid * ROWS;
  const int w  = tid >> 6;   // wave id (= kc slot it fills in phase 1)
  const int l  = tid & 63;   // lane
  const int fr = l & 15;     // frag row (A) / col-in-tile (B,D)
  const int fo = l >> 4;     // k-octet group
  const int r3 = tid >> 5;   // phase-3 row
  const int s3 = tid & 31;   // phase-3 col slot

  float cs;
  { float c = cst[0]; cs = rcp_fast(1.0f + exp2_fast(-c * 1.4426950408889634f)); }

  for (int i = tid; i < ROWS*TS; i += NTH) {
    int r = i >> 7, t = i & 127;
    xidx[r][t] = (unsigned char)(int)(x[((size_t)(r0 + r))*TS + t] + 0.5f);
  }
  for (int i = tid; i < 10*H; i += NTH) {
    int v = i >> 8, k = i & 255;
    emb[v][k] = tanh_fast((float)v * We[k] + be[k]);
  }
  for (int k = tid; k < H; k += NTH) { bu_s[k]=bu[k]; gm_s[k]=gm[k]; bt_s[k]=bt[k]; }
  for (int i = tid; i < ROWS*260; i += NTH) (&hcur[0][0])[i] = 0.0f;

  // W_update fragments live in REGISTERS for the whole kernel (constant across steps).
  // hi+lo bf16 split: activation rounding is then the only per-step bf16 error source.
  // A and B frags use the SAME per-(lane,elem) k index, so results are correct for any
  // HW k-permutation; D layout: col=lane&15, row=(lane>>4)*4+reg (HW-verified).
  bf16x8 whi0[8], wlo0[8], whi1[8], wlo1[8];
  {
    const int c0 = 32*w + fr;
    #pragma unroll
    for (int kc = 0; kc < 8; ++kc) {
      #pragma unroll
      for (int i = 0; i < 8; ++i) {
        int kg = 32*kc + 8*fo + i;
        float w0 = Wu[(size_t)kg*H + c0];
        float w1 = Wu[(size_t)kg*H + c0 + 16];
        unsigned short h0 = bf16_rne(w0), h1 = bf16_rne(w1);
        whi0[kc][i] = (short)h0; wlo0[kc][i] = (short)bf16_rne(w0 - bf16f(h0));
        whi1[kc][i] = (short)h1; wlo1[kc][i] = (short)bf16_rne(w1 - bf16f(h1));
      }
    }
  }
  __syncthreads();

  u16x8 ctx_pre = (u16x8)0;
  const int kbase = 32*w + 8*fo;

  for (int t = 0; t < TS; ++t) {
    // ---- phase 1: A = emb[x_t] + cs*ctx + h  -> bf16 frags ----
    {
      int xv = xidx[fr][t];
      float a[8];
      const float* er = &emb[xv][kbase];
      const float* hr = &hcur[fr][kbase];
      if (use_hist && t >= 64) {
        #pragma unroll
        for (int i = 0; i < 8; ++i) a[i] = er[i] + cs*bf16f((unsigned short)ctx_pre[i]) + hr[i];
      } else {
        #pragma unroll
        for (int i = 0; i < 8; ++i) a[i] = er[i] + hr[i];
      }
      u16x8 pk;
      #pragma unroll
      for (int i = 0; i < 8; ++i) pk[i] = bf16_rne(a[i]);
      *(u16x8*)(&afrag[w][l][0]) = pk;
    }
    __syncthreads();

    // ---- phase 2: 16x256 @ 256x256 via MFMA (hi+lo), +bias, tanh -> hpre ----
    {
      f32x4 acc0 = {0.f,0.f,0.f,0.f}, acc1 = {0.f,0.f,0.f,0.f};
      #pragma unroll
      for (int kc = 0; kc < 8; ++kc) {
        bf16x8 af = *(const bf16x8*)(&afrag[kc][l][0]);
        acc0 = __builtin_amdgcn_mfma_f32_16x16x32_bf16(af, whi0[kc], acc0, 0, 0, 0);
        acc0 = __builtin_amdgcn_mfma_f32_16x16x32_bf16(af, wlo0[kc], acc0, 0, 0, 0);
        acc1 = __builtin_amdgcn_mfma_f32_16x16x32_bf16(af, whi1[kc], acc1, 0, 0, 0);
        acc1 = __builtin_amdgcn_mfma_f32_16x16x32_bf16(af, wlo1[kc], acc1, 0, 0, 0);
      }
      const int c0 = 32*w + fr;
      const int m0 = fo * 4;
      float b0 = bu_s[c0], b1 = bu_s[c0 + 16];
      #pragma unroll
      for (int p = 0; p < 4; ++p) {
        hpre[m0+p][c0]      = tanh_fast(acc0[p] + b0);
        hpre[m0+p][c0 + 16] = tanh_fast(acc1[p] + b1);
      }
    }
    __syncthreads();

    // ---- phase 3: layernorm -> hcur; hist write (t<64); prefetch ctx for t+1 ----
    {
      float v[8], s1 = 0.f, s2 = 0.f;
      #pragma unroll
      for (int i = 0; i < 8; ++i) { float q = hpre[r3][s3 + 32*i]; v[i] = q; s1 += q; s2 += q*q; }
      #pragma unroll
      for (int m = 16; m >= 1; m >>= 1) { s1 += __shfl_xor(s1, m, 64); s2 += __shfl_xor(s2, m, 64); }
      float mu  = s1 * 0.00390625f;
      float var = s2 * 0.00390625f - mu*mu;
      float rs  = rsq_fast(var + 1e-5f);
      unsigned short hb[8];
      #pragma unroll
      for (int i = 0; i < 8; ++i) {
        int k = s3 + 32*i;
        float hv = (v[i] - mu) * rs * gm_s[k] + bt_s[k];
        hcur[r3][k] = hv;
        hb[i] = bf16_rne(hv);
      }
      if (use_hist && t < 64) {
        size_t base = ((size_t)t * BT + (r0 + r3)) * H;
        #pragma unroll
        for (int i = 0; i < 8; ++i) hist[base + s3 + 32*i] = hb[i];
      }
      if (use_hist && (t + 1) >= 64 && (t + 1) < TS) {
        size_t pb = ((size_t)(t + 1 - 64) * BT + (r0 + fr)) * H + kbase;
        ctx_pre = *(const u16x8*)(hist + pb);
      }
    }
    __syncthreads();
  }

  // final projection: out = h @ W_out + b_out  ([16,256]@[256,10] per block)
  if (tid < ROWS * 10) {
    int r = tid / 10, c = tid % 10;
    float acc = bo[c];
    for (int k = 0; k < H; ++k) acc += hcur[r][k] * Wo[k*10 + c];
    out[((size_t)(r0 + r))*10 + c] = acc;
  }
}

extern "C" void kernel_launch(void* const* d_in, const int* in_sizes, int n_in,
                              void* d_out, int out_size, void* d_ws, size_t ws_size,
                              hipStream_t stream) {
  const float* x   = (const float*)d_in[0];
  const float* We  = (const float*)d_in[1];
  const float* be  = (const float*)d_in[2];
  const float* Wu  = (const float*)d_in[3];
  const float* bu  = (const float*)d_in[4];
  const float* gm  = (const float*)d_in[5];
  const float* bt  = (const float*)d_in[6];
  const float* Wo  = (const float*)d_in[7];
  const float* bo  = (const float*)d_in[8];
  const float* cst = (const float*)d_in[9];
  float* out = (float*)d_out;

  size_t need = (size_t)NSLOTS * BT * H * sizeof(unsigned short); // 128 MB history ring
  int use_hist = (ws_size >= need) ? 1 : 0;  // if ws too small: distinct (wrong) signature, no corruption

  hipLaunchKernelGGL(wp_kernel, dim3(NBLK), dim3(NTH), 0, stream,
                     x, We, be, Wu, bu, gm, bt, Wo, bo, cst,
                     (unsigned short*)d_ws, out, use_hist);
}

// Round 2
// 248.252 us; speedup vs baseline: 1.0291x; 1.0291x over previous
//
#include <hip/hip_runtime.h>
#include <stdint.h>

#define H 256
#define BT 4096
#define TS 128
#define ROWS 16
#define NBLK 256   // BT/ROWS
#define NTH 1024   // 16 waves
#define LD 260     // padded row (floats): 16B-aligned rows, bank-friendly

typedef __attribute__((ext_vector_type(8))) short bf16x8;
typedef __attribute__((ext_vector_type(4))) float f32x4;
typedef __attribute__((ext_vector_type(4))) unsigned short u16x4;

__device__ __forceinline__ float exp2_fast(float x){ float r; asm("v_exp_f32 %0, %1" : "=v"(r) : "v"(x)); return r; }
__device__ __forceinline__ float rcp_fast(float x){ float r; asm("v_rcp_f32 %0, %1" : "=v"(r) : "v"(x)); return r; }
__device__ __forceinline__ float rsq_fast(float x){ float r; asm("v_rsq_f32 %0, %1" : "=v"(r) : "v"(x)); return r; }
__device__ __forceinline__ float tanh_fast(float x){
  float e = exp2_fast(x * 2.8853900817779268f);
  return 1.0f - 2.0f * rcp_fast(e + 1.0f);
}
__device__ __forceinline__ unsigned short bf16_rne(float f){
  unsigned u = __float_as_uint(f);
  u += 0x7fffu + ((u >> 16) & 1u);
  return (unsigned short)(u >> 16);
}
__device__ __forceinline__ float bf16f(unsigned short h){ return __uint_as_float(((unsigned)h) << 16); }
// barrier that does NOT drain vmcnt: cross-wave deps are LDS-only; hist ld/st are
// same-wave with 61-step distance, so global ops may stay in flight.
__device__ __forceinline__ void bar_lgkm(){ asm volatile("s_waitcnt lgkmcnt(0)\n\ts_barrier" ::: "memory"); }

__global__ __launch_bounds__(NTH, 4) void wp_kernel(
    const float* __restrict__ x, const float* __restrict__ We, const float* __restrict__ be,
    const float* __restrict__ Wu, const float* __restrict__ bu, const float* __restrict__ gm,
    const float* __restrict__ bt, const float* __restrict__ Wo, const float* __restrict__ bo,
    const float* __restrict__ cst, unsigned short* __restrict__ hist, float* __restrict__ out,
    int use_hist)
{
  __shared__ __align__(16) float emb[10][LD];
  __shared__ __align__(16) float hpre[ROWS][LD];
  __shared__ __align__(16) float hcur[ROWS][LD];
  // A fragments, bf16: plane kc holds A[fr][32kc+8fo+e] at physical row (fr+16*fo)^kc.
  // XOR swizzle makes both the b64 writes (phase3) and b128 reads (phase2) bank-balanced.
  __shared__ __align__(16) unsigned short afrag[8][64][8];
  __shared__ unsigned char xidx[ROWS][TS];
  __shared__ __align__(16) float gm_s[H], bt_s[H];
  __shared__ float bu_s[H];

  const int tid = threadIdx.x;
  const int r0 = blockIdx.x * ROWS;
  const int w  = tid >> 6;          // wave 0..15: N-tile in phase2, row in phase3
  const int l  = tid & 63;
  const int fr = l & 15;
  const int fo = l >> 4;
  const int pcol = 16*w + fr;       // phase2 D column

  float cs;
  { float c = cst[0]; cs = rcp_fast(1.0f + exp2_fast(-c * 1.4426950408889634f)); }

  for (int i = tid; i < ROWS*TS; i += NTH) {
    int r = i >> 7, t = i & 127;
    xidx[r][t] = (unsigned char)(int)(x[((size_t)(r0 + r))*TS + t] + 0.5f);
  }
  for (int i = tid; i < 10*H; i += NTH) {
    int v = i >> 8, k = i & 255;
    emb[v][k] = tanh_fast((float)v * We[k] + be[k]);
  }
  for (int k = tid; k < H; k += NTH) { bu_s[k]=bu[k]; gm_s[k]=gm[k]; bt_s[k]=bt[k]; }

  // W_update hi+lo bf16 fragments in registers (64 VGPRs): one 16-col N-tile per wave.
  // Same per-(lane,elem) k-mapping as the A fragments -> layout-safe; numerics identical
  // to the verified round-1 kernel (hi then lo per kc).
  bf16x8 whi[8], wlo[8];
  {
    #pragma unroll
    for (int kc = 0; kc < 8; ++kc) {
      #pragma unroll
      for (int i = 0; i < 8; ++i) {
        int kg = 32*kc + 8*fo + i;
        float wv = Wu[(size_t)kg*H + pcol];
        unsigned short hh = bf16_rne(wv);
        whi[kc][i] = (short)hh;
        wlo[kc][i] = (short)bf16_rne(wv - bf16f(hh));
      }
    }
  }
  __syncthreads();

  // loop-invariant per-lane values hoisted out of the LDS path
  f32x4 g4 = *(const f32x4*)&gm_s[4*l];
  f32x4 b4 = *(const f32x4*)&bt_s[4*l];
  float bval = bu_s[pcol];

  // prologue: A-frags for t=0 (h=0, no ctx)
  {
    int xv = xidx[w][0];
    f32x4 e = *(const f32x4*)&emb[xv][4*l];
    u16x4 pk;
    #pragma unroll
    for (int j = 0; j < 4; ++j) pk[j] = bf16_rne(e[j]);
    *(u16x4*)&afrag[l>>3][(w + 16*((l>>1)&3)) ^ (l>>3)][4*(l&1)] = pk;
  }
  __syncthreads();

  u16x4 ctxP = {0,0,0,0}, ctxQ = {0,0,0,0};  // 2-deep ctx prefetch pipeline

  for (int t = 0; t < TS; ++t) {
    // ---- phase 2: h_pre = tanh(A @ Wu + bu), one 16-col tile per wave ----
    {
      f32x4 acc = {0.f,0.f,0.f,0.f};
      #pragma unroll
      for (int kc = 0; kc < 8; ++kc) {
        bf16x8 af = *(const bf16x8*)&afrag[kc][l ^ kc][0];
        acc = __builtin_amdgcn_mfma_f32_16x16x32_bf16(af, whi[kc], acc, 0, 0, 0);
        acc = __builtin_amdgcn_mfma_f32_16x16x32_bf16(af, wlo[kc], acc, 0, 0, 0);
      }
      const int m0 = fo * 4;
      #pragma unroll
      for (int p = 0; p < 4; ++p)
        hpre[m0+p][pcol] = tanh_fast(acc[p] + bval);
    }
    bar_lgkm();

    // ---- phase 3: LN (wave w owns row w) + build next A-frags + hist I/O ----
    {
      f32x4 h4 = *(const f32x4*)&hpre[w][4*l];
      float s1 = (h4[0]+h4[1]) + (h4[2]+h4[3]);
      float s2 = h4[0]*h4[0];
      s2 = fmaf(h4[1],h4[1],s2); s2 = fmaf(h4[2],h4[2],s2); s2 = fmaf(h4[3],h4[3],s2);
      #pragma unroll
      for (int m = 1; m <= 32; m <<= 1) { s1 += __shfl_xor(s1, m, 64); s2 += __shfl_xor(s2, m, 64); }
      float mu  = s1 * 0.00390625f;
      float var = s2 * 0.00390625f - mu*mu;
      float rs  = rsq_fast(var + 1e-5f);
      float hv0 = (h4[0]-mu)*rs*g4[0] + b4[0];
      float hv1 = (h4[1]-mu)*rs*g4[1] + b4[1];
      float hv2 = (h4[2]-mu)*rs*g4[2] + b4[2];
      float hv3 = (h4[3]-mu)*rs*g4[3] + b4[3];

      if (t == TS-1) {
        f32x4 hv4 = {hv0, hv1, hv2, hv3};
        *(f32x4*)&hcur[w][4*l] = hv4;
      } else {
        if (use_hist && t < 64) {
          u16x4 hb = { bf16_rne(hv0), bf16_rne(hv1), bf16_rne(hv2), bf16_rne(hv3) };
          *(u16x4*)(hist + ((size_t)t*BT + (size_t)(r0 + w))*H + 4*l) = hb;
        }
        int xv = xidx[w][t+1];
        f32x4 e = *(const f32x4*)&emb[xv][4*l];
        float a0, a1, a2, a3;
        if (use_hist && t >= 63) {
          a0 = e[0] + cs*bf16f(ctxP[0]) + hv0;
          a1 = e[1] + cs*bf16f(ctxP[1]) + hv1;
          a2 = e[2] + cs*bf16f(ctxP[2]) + hv2;
          a3 = e[3] + cs*bf16f(ctxP[3]) + hv3;
        } else {
          a0 = e[0] + hv0; a1 = e[1] + hv1; a2 = e[2] + hv2; a3 = e[3] + hv3;
        }
        u16x4 pk = { bf16_rne(a0), bf16_rne(a1), bf16_rne(a2), bf16_rne(a3) };
        *(u16x4*)&afrag[l>>3][(w + 16*((l>>1)&3)) ^ (l>>3)][4*(l&1)] = pk;

        ctxP = ctxQ;   // used at phase3(t+1)
        if (use_hist && t >= 61 && t + 3 < TS)  // arrives for use at phase3(t+2)
          ctxQ = *(const u16x4*)(hist + ((size_t)(t-61)*BT + (size_t)(r0 + w))*H + 4*l);
      }
    }
    bar_lgkm();
  }

  // final projection: out = h @ W_out + b_out  ([16,256]@[256,10] per block)
  if (tid < ROWS * 10) {
    int r = tid / 10, c = tid % 10;
    float acc = bo[c];
    for (int k = 0; k < H; ++k) acc += hcur[r][k] * Wo[k*10 + c];
    out[((size_t)(r0 + r))*10 + c] = acc;
  }
}

extern "C" void kernel_launch(void* const* d_in, const int* in_sizes, int n_in,
                              void* d_out, int out_size, void* d_ws, size_t ws_size,
                              hipStream_t stream) {
  const float* x   = (const float*)d_in[0];
  const float* We  = (const float*)d_in[1];
  const float* be  = (const float*)d_in[2];
  const float* Wu  = (const float*)d_in[3];
  const float* bu  = (const float*)d_in[4];
  const float* gm  = (const float*)d_in[5];
  const float* bt  = (const float*)d_in[6];
  const float* Wo  = (const float*)d_in[7];
  const float* bo  = (const float*)d_in[8];
  const float* cst = (const float*)d_in[9];
  float* out = (float*)d_out;

  size_t need = (size_t)64 * BT * H * sizeof(unsigned short); // 128 MB history ring
  int use_hist = (ws_size >= need) ? 1 : 0;

  hipLaunchKernelGGL(wp_kernel, dim3(NBLK), dim3(NTH), 0, stream,
                     x, We, be, Wu, bu, gm, bt, Wo, bo, cst,
                     (unsigned short*)d_ws, out, use_hist);
}

// Round 3
// 234.683 us; speedup vs baseline: 1.0886x; 1.0578x over previous
//
#include <hip/hip_runtime.h>
#include <stdint.h>

#define H 256
#define BT 4096
#define TS 128
#define ROWS 16
#define NBLK 256   // BT/ROWS, 1 block per CU (recurrence forces co-residency of 16 rows)
#define NTH 512    // 8 waves
#define LD 260     // padded row (floats): 16B-aligned rows, 2-way banks max
#define PST 18     // part[] stride: 8B-aligned float2, conflict-free (18r+s distinct mod 32)

typedef __attribute__((ext_vector_type(8))) short bf16x8;
typedef __attribute__((ext_vector_type(4))) float f32x4;
typedef __attribute__((ext_vector_type(4))) unsigned short u16x4;

__device__ __forceinline__ float exp2_fast(float x){ float r; asm("v_exp_f32 %0, %1" : "=v"(r) : "v"(x)); return r; }
__device__ __forceinline__ float rcp_fast(float x){ float r; asm("v_rcp_f32 %0, %1" : "=v"(r) : "v"(x)); return r; }
__device__ __forceinline__ float rsq_fast(float x){ float r; asm("v_rsq_f32 %0, %1" : "=v"(r) : "v"(x)); return r; }
__device__ __forceinline__ float tanh_fast(float x){
  float e = exp2_fast(x * 2.8853900817779268f);
  return 1.0f - 2.0f * rcp_fast(e + 1.0f);
}
__device__ __forceinline__ unsigned short bf16_rne(float f){
  unsigned u = __float_as_uint(f);
  u += 0x7fffu + ((u >> 16) & 1u);
  return (unsigned short)(u >> 16);
}
__device__ __forceinline__ float bf16f(unsigned short h){ return __uint_as_float(((unsigned)h) << 16); }
// barrier w/o vmcnt drain: cross-wave deps are LDS-only; hist ld/st are same-wave, 61 steps apart
__device__ __forceinline__ void bar_lgkm(){ asm volatile("s_waitcnt lgkmcnt(0)\n\ts_barrier" ::: "memory"); }

// VALU-pipe cross-lane add: x += rotate-right-within-16(x, N). Replaces DS-pipe shuffles.
template<int CTRL>
__device__ __forceinline__ float ror_add(float x){
  int y = __builtin_amdgcn_update_dpp(0, __float_as_int(x), CTRL, 0xf, 0xf, false);
  return x + __int_as_float(y);
}
// row_ror:n = 0x120+n
#define ROR1 0x121
#define ROR2 0x122
#define ROR4 0x124
#define ROR8 0x128

__global__ __launch_bounds__(NTH, 2) void wp_kernel(
    const float* __restrict__ x, const float* __restrict__ We, const float* __restrict__ be,
    const float* __restrict__ Wu, const float* __restrict__ bu, const float* __restrict__ gm,
    const float* __restrict__ bt, const float* __restrict__ Wo, const float* __restrict__ bo,
    const float* __restrict__ cst, unsigned short* __restrict__ hist, float* __restrict__ out,
    int use_hist)
{
  __shared__ __align__(16) float emb[10][LD];
  __shared__ __align__(16) float hpre[ROWS][LD];
  // A fragments: plane kc holds A[fr][32kc+8fo+e] at physical row (fr+16*fo)^kc (conflict-proven r2)
  __shared__ __align__(16) unsigned short afrag[8][64][8];
  __shared__ __align__(16) float part[ROWS][PST];   // per-row (s1,s2) partials from 8 waves
  __shared__ unsigned char xidx[ROWS][TS];

  const int tid = threadIdx.x;
  const int r0 = blockIdx.x * ROWS;
  const int w  = tid >> 6;        // wave 0..7: N-tile pair (cols 32w..32w+32), rows {2w,2w+1}
  const int l  = tid & 63;
  const int fr = l & 15;
  const int fo = l >> 4;
  const int ra = 2*w, rb = 2*w + 1;
  const int c0 = 32*w + fr, c1 = 32*w + 16 + fr;

  float cs;
  { float c = cst[0]; cs = rcp_fast(1.0f + exp2_fast(-c * 1.4426950408889634f)); }

  for (int i = tid; i < ROWS*TS; i += NTH) {
    int r = i >> 7, t = i & 127;
    xidx[r][t] = (unsigned char)(int)(x[((size_t)(r0 + r))*TS + t] + 0.5f);
  }
  for (int i = tid; i < 10*H; i += NTH) {
    int v = i >> 8, k = i & 255;
    emb[v][k] = tanh_fast((float)v * We[k] + be[k]);
  }

  // W_update hi+lo bf16 fragments in registers (128 VGPR): two 16-col N-tiles per wave.
  // Same per-(lane,elem) k-mapping as A frags -> layout-safe (r1/r2 verified numerics).
  bf16x8 whi0[8], wlo0[8], whi1[8], wlo1[8];
  #pragma unroll
  for (int kc = 0; kc < 8; ++kc) {
    #pragma unroll
    for (int i = 0; i < 8; ++i) {
      int kg = 32*kc + 8*fo + i;
      float w0 = Wu[(size_t)kg*H + c0];
      float w1 = Wu[(size_t)kg*H + c1];
      unsigned short h0 = bf16_rne(w0), h1 = bf16_rne(w1);
      whi0[kc][i] = (short)h0; wlo0[kc][i] = (short)bf16_rne(w0 - bf16f(h0));
      whi1[kc][i] = (short)h1; wlo1[kc][i] = (short)bf16_rne(w1 - bf16f(h1));
    }
  }
  float bval0 = bu[c0], bval1 = bu[c1];
  f32x4 g4 = *(const f32x4*)(gm + 4*l);
  f32x4 b4 = *(const f32x4*)(bt + 4*l);
  __syncthreads();

  // prologue: A-frags for t=0 (h=0, no ctx) for rows ra, rb
  {
    int xv = xidx[ra][0];
    f32x4 e4 = *(const f32x4*)&emb[xv][4*l];
    u16x4 pk = { bf16_rne(e4[0]), bf16_rne(e4[1]), bf16_rne(e4[2]), bf16_rne(e4[3]) };
    *(u16x4*)&afrag[l>>3][(ra + 16*((l>>1)&3)) ^ (l>>3)][4*(l&1)] = pk;
    xv = xidx[rb][0];
    e4 = *(const f32x4*)&emb[xv][4*l];
    u16x4 pk2 = { bf16_rne(e4[0]), bf16_rne(e4[1]), bf16_rne(e4[2]), bf16_rne(e4[3]) };
    *(u16x4*)&afrag[l>>3][(rb + 16*((l>>1)&3)) ^ (l>>3)][4*(l&1)] = pk2;
  }
  __syncthreads();

  u16x4 ctxPa = {0,0,0,0}, ctxQa = {0,0,0,0};
  u16x4 ctxPb = {0,0,0,0}, ctxQb = {0,0,0,0};

  for (int t = 0; t < TS; ++t) {
    // ---- phase 2: h_pre = tanh(A @ Wu + bu), 2 N-tiles/wave; LN partial sums via DPP ----
    {
      f32x4 acc0 = {0.f,0.f,0.f,0.f}, acc1 = {0.f,0.f,0.f,0.f};
      #pragma unroll
      for (int kc = 0; kc < 8; ++kc) {
        bf16x8 af = *(const bf16x8*)&afrag[kc][l ^ kc][0];
        acc0 = __builtin_amdgcn_mfma_f32_16x16x32_bf16(af, whi0[kc], acc0, 0, 0, 0);
        acc0 = __builtin_amdgcn_mfma_f32_16x16x32_bf16(af, wlo0[kc], acc0, 0, 0, 0);
        acc1 = __builtin_amdgcn_mfma_f32_16x16x32_bf16(af, whi1[kc], acc1, 0, 0, 0);
        acc1 = __builtin_amdgcn_mfma_f32_16x16x32_bf16(af, wlo1[kc], acc1, 0, 0, 0);
      }
      const int m0 = 4*fo;
      float s1v[4], s2v[4];     // constant-indexed after unroll -> registers
      #pragma unroll
      for (int p = 0; p < 4; ++p) {
        float t0 = tanh_fast(acc0[p] + bval0);
        float t1 = tanh_fast(acc1[p] + bval1);
        hpre[m0+p][c0] = t0;
        hpre[m0+p][c1] = t1;
        float a = t0 + t1;
        float b = fmaf(t0, t0, t1*t1);
        a = ror_add<ROR1>(a); a = ror_add<ROR2>(a); a = ror_add<ROR4>(a); a = ror_add<ROR8>(a);
        b = ror_add<ROR1>(b); b = ror_add<ROR2>(b); b = ror_add<ROR4>(b); b = ror_add<ROR8>(b);
        s1v[p] = a; s2v[p] = b;
      }
      // writer lanes fr<8: row = m0+(fr&3), stat = fr>>2 (0:s1, 1:s2)
      float w01 = (fr & 1) ? s1v[1] : s1v[0];
      float w23 = (fr & 1) ? s1v[3] : s1v[2];
      float z01 = (fr & 1) ? s2v[1] : s2v[0];
      float z23 = (fr & 1) ? s2v[3] : s2v[2];
      float wv = (fr & 2) ? w23 : w01;
      float zv = (fr & 2) ? z23 : z01;
      float pv = (fr & 4) ? zv : wv;
      if (fr < 8) part[m0 + (fr & 3)][2*w + (fr >> 2)] = pv;
    }
    bar_lgkm();

    // ---- phase 3: LN + next A-frags + hist I/O; wave w owns rows 2w, 2w+1 ----
    {
      f32x4 h4a = *(const f32x4*)&hpre[ra][4*l];
      f32x4 h4b = *(const f32x4*)&hpre[rb][4*l];
      float2 pra = *(const float2*)&part[ra][2*(l&7)];
      float2 prb = *(const float2*)&part[rb][2*(l&7)];
      int xva = 0, xvb = 0;
      if (t < TS-1) { xva = xidx[ra][t+1]; xvb = xidx[rb][t+1]; }

      auto p3 = [&](int r, f32x4 h4, float2 pr, u16x4& ctxP, u16x4& ctxQ, int xv) {
        float s1 = pr.x, s2 = pr.y;   // partials of wave (l&7), period-8 in each 16-row
        s1 = ror_add<ROR1>(s1); s1 = ror_add<ROR2>(s1); s1 = ror_add<ROR4>(s1);
        s2 = ror_add<ROR1>(s2); s2 = ror_add<ROR2>(s2); s2 = ror_add<ROR4>(s2);
        float mu  = s1 * 0.00390625f;
        float var = s2 * 0.00390625f - mu*mu;
        float rs  = rsq_fast(var + 1e-5f);
        float hv0 = (h4[0]-mu)*rs*g4[0] + b4[0];
        float hv1 = (h4[1]-mu)*rs*g4[1] + b4[1];
        float hv2 = (h4[2]-mu)*rs*g4[2] + b4[2];
        float hv3 = (h4[3]-mu)*rs*g4[3] + b4[3];
        if (t == TS-1) {
          f32x4 o = {hv0,hv1,hv2,hv3};
          *(f32x4*)&hpre[r][4*l] = o;
          return;
        }
        if (use_hist && t < 64) {
          u16x4 hb = { bf16_rne(hv0), bf16_rne(hv1), bf16_rne(hv2), bf16_rne(hv3) };
          *(u16x4*)(hist + ((size_t)t*BT + (size_t)(r0 + r))*H + 4*l) = hb;
        }
        f32x4 e4 = *(const f32x4*)&emb[xv][4*l];
        float a0, a1, a2, a3;
        if (use_hist && t >= 63) {
          a0 = e4[0] + cs*bf16f(ctxP[0]) + hv0;
          a1 = e4[1] + cs*bf16f(ctxP[1]) + hv1;
          a2 = e4[2] + cs*bf16f(ctxP[2]) + hv2;
          a3 = e4[3] + cs*bf16f(ctxP[3]) + hv3;
        } else {
          a0 = e4[0] + hv0; a1 = e4[1] + hv1; a2 = e4[2] + hv2; a3 = e4[3] + hv3;
        }
        u16x4 pk = { bf16_rne(a0), bf16_rne(a1), bf16_rne(a2), bf16_rne(a3) };
        *(u16x4*)&afrag[l>>3][(r + 16*((l>>1)&3)) ^ (l>>3)][4*(l&1)] = pk;
        ctxP = ctxQ;    // used at phase3(t+1)
        if (use_hist && t >= 61 && t + 3 < TS)   // arrives for use at phase3(t+2)
          ctxQ = *(const u16x4*)(hist + ((size_t)(t-61)*BT + (size_t)(r0 + r))*H + 4*l);
      };
      p3(ra, h4a, pra, ctxPa, ctxQa, xva);
      p3(rb, h4b, prb, ctxPb, ctxQb, xvb);
    }
    bar_lgkm();
  }

  __syncthreads();
  // final projection: out = h @ W_out + b_out  ([16,256]@[256,10] per block)
  if (tid < ROWS * 10) {
    int r = tid / 10, c = tid % 10;
    float acc = bo[c];
    for (int k = 0; k < H; ++k) acc += hpre[r][k] * Wo[k*10 + c];
    out[((size_t)(r0 + r))*10 + c] = acc;
  }
}

extern "C" void kernel_launch(void* const* d_in, const int* in_sizes, int n_in,
                              void* d_out, int out_size, void* d_ws, size_t ws_size,
                              hipStream_t stream) {
  const float* x   = (const float*)d_in[0];
  const float* We  = (const float*)d_in[1];
  const float* be  = (const float*)d_in[2];
  const float* Wu  = (const float*)d_in[3];
  const float* bu  = (const float*)d_in[4];
  const float* gm  = (const float*)d_in[5];
  const float* bt  = (const float*)d_in[6];
  const float* Wo  = (const float*)d_in[7];
  const float* bo  = (const float*)d_in[8];
  const float* cst = (const float*)d_in[9];
  float* out = (float*)d_out;

  size_t need = (size_t)64 * BT * H * sizeof(unsigned short); // 128 MB history ring
  int use_hist = (ws_size >= need) ? 1 : 0;

  hipLaunchKernelGGL(wp_kernel, dim3(NBLK), dim3(NTH), 0, stream,
                     x, We, be, Wu, bu, gm, bt, Wo, bo, cst,
                     (unsigned short*)d_ws, out, use_hist);
}

// Round 4
// 225.971 us; speedup vs baseline: 1.1306x; 1.0386x over previous
//
#include <hip/hip_runtime.h>
#include <hip/hip_bf16.h>
#include <stdint.h>

#define H 256
#define BT 4096
#define TS 128
#define ROWS 16
#define NBLK 256   // BT/ROWS, 1 block per CU
#define NTH 512    // 8 waves
#define LD 260     // padded row (floats)

typedef __attribute__((ext_vector_type(8))) short bf16x8;
typedef __attribute__((ext_vector_type(4))) float f32x4;

__device__ __forceinline__ float exp2_fast(float x){ float r; asm("v_exp_f32 %0, %1" : "=v"(r) : "v"(x)); return r; }
__device__ __forceinline__ float rcp_fast(float x){ float r; asm("v_rcp_f32 %0, %1" : "=v"(r) : "v"(x)); return r; }
__device__ __forceinline__ float rsq_fast(float x){ float r; asm("v_rsq_f32 %0, %1" : "=v"(r) : "v"(x)); return r; }
__device__ __forceinline__ float tanh_fast(float x){
  float e = exp2_fast(x * 2.8853900817779268f);
  return 1.0f - 2.0f * rcp_fast(e + 1.0f);
}
__device__ __forceinline__ unsigned short bf16_rne(float f){   // init-time only
  unsigned u = __float_as_uint(f);
  u += 0x7fffu + ((u >> 16) & 1u);
  return (unsigned short)(u >> 16);
}
__device__ __forceinline__ float bf16f(unsigned short h){ return __uint_as_float(((unsigned)h) << 16); }
// packed RNE f32->bf16 pair; compiler emits v_cvt_pk_bf16_f32 (same rounding as bf16_rne)
__device__ __forceinline__ unsigned pk_bf16(float a, float b){
  __hip_bfloat162 h2 = __float22bfloat162_rn(make_float2(a, b));
  union { __hip_bfloat162 h; unsigned u; } cv; cv.h = h2; return cv.u;   // x in low 16
}
// barrier w/o vmcnt drain: cross-wave deps are LDS-only; hist ld/st are same-wave, 61 steps apart
__device__ __forceinline__ void bar_lgkm(){ asm volatile("s_waitcnt lgkmcnt(0)\n\ts_barrier" ::: "memory"); }

template<int CTRL>
__device__ __forceinline__ float ror_add(float x){
  int y = __builtin_amdgcn_update_dpp(0, __float_as_int(x), CTRL, 0xf, 0xf, false);
  return x + __int_as_float(y);
}
#define ROR1 0x121
#define ROR2 0x122
#define ROR4 0x124
#define ROR8 0x128
__device__ __forceinline__ float lane_f(float v, int n){
  return __int_as_float(__builtin_amdgcn_readlane(__float_as_int(v), n));
}

__global__ __launch_bounds__(NTH, 2) void wp_kernel(
    const float* __restrict__ x, const float* __restrict__ We, const float* __restrict__ be,
    const float* __restrict__ Wu, const float* __restrict__ bu, const float* __restrict__ gm,
    const float* __restrict__ bt, const float* __restrict__ Wo, const float* __restrict__ bo,
    const float* __restrict__ cst, unsigned short* __restrict__ hist, float* __restrict__ out,
    int use_hist)
{
  __shared__ __align__(16) float emb[10][LD];
  __shared__ __align__(16) float hpre[ROWS][LD];
  // A frags: element k=32kc+8fo'+4e'+j of row r lives in plane kc, physical row
  // (r+16fo')^kc^(2fo'), halfwords 4e'+j. Reads: per-quarter permutation (conflict-free);
  // writes: fo' spread across 4 bank groups (conflict-free, fixes r3's 192cyc/step).
  __shared__ __align__(16) unsigned short afrag[8][64][8];
  __shared__ unsigned char xidx[ROWS][TS];

  const int tid = threadIdx.x;
  const int r0 = blockIdx.x * ROWS;
  const int w  = tid >> 6;        // wave: N-cols [32w,32w+32); rows {2w, 2w+1}
  const int l  = tid & 63;
  const int fr = l & 15;
  const int fo = l >> 4;
  const int ra = 2*w, rb = 2*w + 1;
  const int c0 = 32*w + fr, c1 = c0 + 16;

  float cs;
  { float c = cst[0]; cs = rcp_fast(1.0f + exp2_fast(-c * 1.4426950408889634f)); }

  for (int i = tid; i < ROWS*TS; i += NTH) {
    int r = i >> 7, t = i & 127;
    xidx[r][t] = (unsigned char)(int)(x[((size_t)(r0 + r))*TS + t] + 0.5f);
  }
  for (int i = tid; i < 10*H; i += NTH) {
    int v = i >> 8, k = i & 255;
    emb[v][k] = tanh_fast((float)v * We[k] + be[k]);
  }

  // W_update hi+lo bf16 frags in registers/AGPRs (same numerics as r1-r3)
  bf16x8 whi0[8], wlo0[8], whi1[8], wlo1[8];
  #pragma unroll
  for (int kc = 0; kc < 8; ++kc) {
    #pragma unroll
    for (int i = 0; i < 8; ++i) {
      int kg = 32*kc + 8*fo + i;
      float w0 = Wu[(size_t)kg*H + c0];
      float w1 = Wu[(size_t)kg*H + c1];
      unsigned short h0 = bf16_rne(w0), h1 = bf16_rne(w1);
      whi0[kc][i] = (short)h0; wlo0[kc][i] = (short)bf16_rne(w0 - bf16f(h0));
      whi1[kc][i] = (short)h1; wlo1[kc][i] = (short)bf16_rne(w1 - bf16f(h1));
    }
  }
  float bval0 = bu[c0], bval1 = bu[c1];
  f32x4 g4 = *(const f32x4*)(gm + 4*l);
  f32x4 b4 = *(const f32x4*)(bt + 4*l);

  // ---- per-thread-constant addresses (all loop-invariant) ----
  const int XR = l ^ ((l >> 3) & 6);                 // read row base: ^kc per plane
  const int wkc = l >> 3, wfo = (l >> 1) & 3, we = l & 1;
  unsigned short* const awA = &afrag[wkc][(ra + 16*wfo) ^ wkc ^ (2*wfo)][4*we];
  unsigned short* const awB = &afrag[wkc][(rb + 16*wfo) ^ wkc ^ (2*wfo)][4*we];
  const float* const h4pA = &hpre[ra][4*l];
  const float* const h4pB = &hpre[rb][4*l];
  float* const ffinA = &hpre[ra][4*l];
  float* const ffinB = &hpre[rb][4*l];
  const unsigned char* const xrA = &xidx[ra][0];
  const unsigned char* const xrB = &xidx[rb][0];
  const size_t histLaneA = (size_t)(r0 + ra)*H + 4*l;
  const size_t histLaneB = (size_t)(r0 + rb)*H + 4*l;
  __syncthreads();

  // prologue: A-frags for t=0 (h=0, no ctx)
  {
    int xv = xrA[0];
    f32x4 e4 = *(const f32x4*)&emb[xv][4*l];
    uint2 p = { pk_bf16(e4[0], e4[1]), pk_bf16(e4[2], e4[3]) };
    *(uint2*)awA = p;
    xv = xrB[0];
    e4 = *(const f32x4*)&emb[xv][4*l];
    uint2 q = { pk_bf16(e4[0], e4[1]), pk_bf16(e4[2], e4[3]) };
    *(uint2*)awB = q;
  }
  __syncthreads();

  uint2 ctxPa = {0,0}, ctxQa = {0,0}, ctxPb = {0,0}, ctxQb = {0,0};

  for (int t = 0; t < TS; ++t) {
    // ---- phase 2: h_pre = tanh(A @ Wu + bu); 2 N-tiles/wave ----
    {
      f32x4 acc0 = {0.f,0.f,0.f,0.f}, acc1 = {0.f,0.f,0.f,0.f};
      #pragma unroll
      for (int kc = 0; kc < 8; ++kc) {
        bf16x8 af = *(const bf16x8*)&afrag[kc][XR ^ kc][0];
        acc0 = __builtin_amdgcn_mfma_f32_16x16x32_bf16(af, whi0[kc], acc0, 0, 0, 0);
        acc0 = __builtin_amdgcn_mfma_f32_16x16x32_bf16(af, wlo0[kc], acc0, 0, 0, 0);
        acc1 = __builtin_amdgcn_mfma_f32_16x16x32_bf16(af, whi1[kc], acc1, 0, 0, 0);
        acc1 = __builtin_amdgcn_mfma_f32_16x16x32_bf16(af, wlo1[kc], acc1, 0, 0, 0);
      }
      const int m0 = 4*fo;
      #pragma unroll
      for (int p = 0; p < 4; ++p) {
        hpre[m0+p][c0] = tanh_fast(acc0[p] + bval0);
        hpre[m0+p][c1] = tanh_fast(acc1[p] + bval1);
      }
    }
    bar_lgkm();

    // ---- phase 3: LN + next A-frags + hist I/O; wave w owns rows ra, rb ----
    {
      const size_t woff = (size_t)t * (BT*H);          // scalar (SALU)
      const size_t roff = (size_t)(t - 61) * (BT*H);
      const int tln = t;

      auto prow = [&](const float* h4p, unsigned short* aw, const unsigned char* xr,
                      size_t histLane, float* ffin, uint2& cP, uint2& cQ) {
        f32x4 h4 = *(const f32x4*)h4p;
        float s1 = (h4[0]+h4[1]) + (h4[2]+h4[3]);
        float s2 = h4[0]*h4[0];
        s2 = fmaf(h4[1],h4[1],s2); s2 = fmaf(h4[2],h4[2],s2); s2 = fmaf(h4[3],h4[3],s2);
        s1 = ror_add<ROR1>(s1); s1 = ror_add<ROR2>(s1); s1 = ror_add<ROR4>(s1); s1 = ror_add<ROR8>(s1);
        s2 = ror_add<ROR1>(s2); s2 = ror_add<ROR2>(s2); s2 = ror_add<ROR4>(s2); s2 = ror_add<ROR8>(s2);
        float S1 = (lane_f(s1,0) + lane_f(s1,16)) + (lane_f(s1,32) + lane_f(s1,48));
        float S2 = (lane_f(s2,0) + lane_f(s2,16)) + (lane_f(s2,32) + lane_f(s2,48));
        float mu  = S1 * 0.00390625f;
        float var = S2 * 0.00390625f - mu*mu;
        float rs  = rsq_fast(var + 1e-5f);
        float p0 = rs*g4[0], p1 = rs*g4[1], p2 = rs*g4[2], p3 = rs*g4[3];
        float hv0 = fmaf(h4[0]-mu, p0, b4[0]);
        float hv1 = fmaf(h4[1]-mu, p1, b4[1]);
        float hv2 = fmaf(h4[2]-mu, p2, b4[2]);
        float hv3 = fmaf(h4[3]-mu, p3, b4[3]);
        if (tln == TS-1) {
          f32x4 o = {hv0,hv1,hv2,hv3};
          *(f32x4*)ffin = o;
          return;
        }
        if (use_hist && tln < 64) {
          uint2 hb = { pk_bf16(hv0,hv1), pk_bf16(hv2,hv3) };
          *(uint2*)(hist + woff + histLane) = hb;
        }
        int xv = xr[tln+1];
        f32x4 e4 = *(const f32x4*)&emb[xv][4*l];
        float a0, a1, a2, a3;
        if (use_hist && tln >= 63) {
          float cf0 = __uint_as_float(cP.x << 16);
          float cf1 = __uint_as_float(cP.x & 0xffff0000u);
          float cf2 = __uint_as_float(cP.y << 16);
          float cf3 = __uint_as_float(cP.y & 0xffff0000u);
          a0 = fmaf(cs, cf0, e4[0] + hv0);
          a1 = fmaf(cs, cf1, e4[1] + hv1);
          a2 = fmaf(cs, cf2, e4[2] + hv2);
          a3 = fmaf(cs, cf3, e4[3] + hv3);
        } else {
          a0 = e4[0] + hv0; a1 = e4[1] + hv1; a2 = e4[2] + hv2; a3 = e4[3] + hv3;
        }
        uint2 pkk = { pk_bf16(a0,a1), pk_bf16(a2,a3) };
        *(uint2*)aw = pkk;
        cP = cQ;                                        // used at phase3(t+1)
        if (use_hist && tln >= 61 && tln + 3 < TS)      // arrives for use at phase3(t+2)
          cQ = *(const uint2*)(hist + roff + histLane);
      };
      prow(h4pA, awA, xrA, histLaneA, ffinA, ctxPa, ctxQa);
      prow(h4pB, awB, xrB, histLaneB, ffinB, ctxPb, ctxQb);
    }
    bar_lgkm();
  }

  __syncthreads();
  // final projection: out = h @ W_out + b_out  ([16,256]@[256,10] per block)
  if (tid < ROWS * 10) {
    int r = tid / 10, c = tid % 10;
    float acc = bo[c];
    for (int k = 0; k < H; ++k) acc += hpre[r][k] * Wo[k*10 + c];
    out[((size_t)(r0 + r))*10 + c] = acc;
  }
}

extern "C" void kernel_launch(void* const* d_in, const int* in_sizes, int n_in,
                              void* d_out, int out_size, void* d_ws, size_t ws_size,
                              hipStream_t stream) {
  const float* x   = (const float*)d_in[0];
  const float* We  = (const float*)d_in[1];
  const float* be  = (const float*)d_in[2];
  const float* Wu  = (const float*)d_in[3];
  const float* bu  = (const float*)d_in[4];
  const float* gm  = (const float*)d_in[5];
  const float* bt  = (const float*)d_in[6];
  const float* Wo  = (const float*)d_in[7];
  const float* bo  = (const float*)d_in[8];
  const float* cst = (const float*)d_in[9];
  float* out = (float*)d_out;

  size_t need = (size_t)64 * BT * H * sizeof(unsigned short); // 128 MB history ring
  int use_hist = (ws_size >= need) ? 1 : 0;

  hipLaunchKernelGGL(wp_kernel, dim3(NBLK), dim3(NTH), 0, stream,
                     x, We, be, Wu, bu, gm, bt, Wo, bo, cst,
                     (unsigned short*)d_ws, out, use_hist);
}

// Round 5
// 201.281 us; speedup vs baseline: 1.2693x; 1.1227x over previous
//
#include <hip/hip_runtime.h>
#include <hip/hip_bf16.h>
#include <stdint.h>

#define H 256
#define BT 4096
#define TS 128
#define ROWS 16
#define NBLK 256   // BT/ROWS, 1 block per CU
#define NTH 1024   // 16 waves, 4/SIMD
#define LD 260     // padded row (floats)

typedef __attribute__((ext_vector_type(8))) short bf16x8;
typedef __attribute__((ext_vector_type(4))) float f32x4;

__device__ __forceinline__ float exp2_fast(float x){ float r; asm("v_exp_f32 %0, %1" : "=v"(r) : "v"(x)); return r; }
__device__ __forceinline__ float rcp_fast(float x){ float r; asm("v_rcp_f32 %0, %1" : "=v"(r) : "v"(x)); return r; }
__device__ __forceinline__ float rsq_fast(float x){ float r; asm("v_rsq_f32 %0, %1" : "=v"(r) : "v"(x)); return r; }
__device__ __forceinline__ float tanh_fast(float x){
  float e = exp2_fast(x * 2.8853900817779268f);
  return 1.0f - 2.0f * rcp_fast(e + 1.0f);
}
__device__ __forceinline__ unsigned short bf16_rne(float f){   // init-time only
  unsigned u = __float_as_uint(f);
  u += 0x7fffu + ((u >> 16) & 1u);
  return (unsigned short)(u >> 16);
}
__device__ __forceinline__ float bf16f(unsigned short h){ return __uint_as_float(((unsigned)h) << 16); }
// packed RNE f32->bf16 pair (v_cvt_pk_bf16_f32), same rounding as bf16_rne
__device__ __forceinline__ unsigned pk_bf16(float a, float b){
  __hip_bfloat162 h2 = __float22bfloat162_rn(make_float2(a, b));
  union { __hip_bfloat162 h; unsigned u; } cv; cv.h = h2; return cv.u;   // a in low 16
}
// barrier w/o vmcnt drain: cross-wave deps are LDS-only; hist ld/st are same-wave, 61+ steps apart
__device__ __forceinline__ void bar_lgkm(){ asm volatile("s_waitcnt lgkmcnt(0)\n\ts_barrier" ::: "memory"); }

template<int CTRL>
__device__ __forceinline__ float ror_add(float x){
  int y = __builtin_amdgcn_update_dpp(0, __float_as_int(x), CTRL, 0xf, 0xf, false);
  return x + __int_as_float(y);
}
#define ROR1 0x121
#define ROR2 0x122
#define ROR4 0x124
#define ROR8 0x128
__device__ __forceinline__ float lane_f(float v, int n){
  return __int_as_float(__builtin_amdgcn_readlane(__float_as_int(v), n));
}

__global__ __launch_bounds__(NTH, 4) void wp_kernel(
    const float* __restrict__ x, const float* __restrict__ We, const float* __restrict__ be,
    const float* __restrict__ Wu, const float* __restrict__ bu, const float* __restrict__ gm,
    const float* __restrict__ bt, const float* __restrict__ Wo, const float* __restrict__ bo,
    const float* __restrict__ cst, unsigned short* __restrict__ hist, float* __restrict__ out,
    int use_hist)
{
  __shared__ __align__(16) float emb[10][LD];
  __shared__ __align__(16) float hpre[ROWS][LD];
  // A frags: element k=32kc+8fo'+4e'+j of row r lives in plane kc, physical row
  // (r+16fo')^kc^(2fo'). Reads b128 + writes b64 both conflict-free (HW-verified r4: SQ_LDS_BANK_CONFLICT=0)
  __shared__ __align__(16) unsigned short afrag[8][64][8];
  __shared__ unsigned char xidx[ROWS][TS];

  const int tid = threadIdx.x;
  const int r0 = blockIdx.x * ROWS;
  const int w  = tid >> 6;        // wave 0..15: N-cols [16w,16w+16) in phase2; row w in phase3
  const int l  = tid & 63;
  const int fr = l & 15;
  const int fo = l >> 4;
  const int c0 = 16*w + fr;       // phase2 D column

  float cs;
  { float c = cst[0]; cs = rcp_fast(1.0f + exp2_fast(-c * 1.4426950408889634f)); }

  for (int i = tid; i < ROWS*TS; i += NTH) {
    int r = i >> 7, t = i & 127;
    xidx[r][t] = (unsigned char)(int)(x[((size_t)(r0 + r))*TS + t] + 0.5f);
  }
  for (int i = tid; i < 10*H; i += NTH) {
    int v = i >> 8, k = i & 255;
    emb[v][k] = tanh_fast((float)v * We[k] + be[k]);
  }

  // W_update hi+lo bf16 frags (64 regs -> AGPRs); numerics identical to r1-r4
  bf16x8 whi[8], wlo[8];
  #pragma unroll
  for (int kc = 0; kc < 8; ++kc) {
    #pragma unroll
    for (int i = 0; i < 8; ++i) {
      int kg = 32*kc + 8*fo + i;
      float wv = Wu[(size_t)kg*H + c0];
      unsigned short hh = bf16_rne(wv);
      whi[kc][i] = (short)hh;
      wlo[kc][i] = (short)bf16_rne(wv - bf16f(hh));
    }
  }
  float bval = bu[c0];
  f32x4 g4 = *(const f32x4*)(gm + 4*l);
  f32x4 b4 = *(const f32x4*)(bt + 4*l);

  // per-thread-constant addresses (loop-invariant)
  const int XR = l ^ (2*fo);                    // phase2 read row base (^kc per plane)
  const int wkc = l >> 3, wfo = (l >> 1) & 3, we = l & 1;
  unsigned short* const aw = &afrag[wkc][(w + 16*wfo) ^ wkc ^ (2*wfo)][4*we];
  const float* const h4p = &hpre[w][4*l];
  float* const ffin = &hpre[w][4*l];
  const unsigned char* const xr = &xidx[w][0];
  const size_t histLane = (size_t)(r0 + w)*H + 4*l;
  __syncthreads();

  // prologue: A-frags for t=0 (h=0, no ctx)
  {
    int xv = xr[0];
    f32x4 e4 = *(const f32x4*)&emb[xv][4*l];
    uint2 p = { pk_bf16(e4[0], e4[1]), pk_bf16(e4[2], e4[3]) };
    *(uint2*)aw = p;
  }
  __syncthreads();

  uint2 cP = {0,0}, cQ = {0,0};

#define PHASE2() do { \
    f32x4 acc = {0.f,0.f,0.f,0.f}; \
    _Pragma("unroll") \
    for (int kc = 0; kc < 8; ++kc) { \
      bf16x8 af = *(const bf16x8*)&afrag[kc][XR ^ kc][0]; \
      acc = __builtin_amdgcn_mfma_f32_16x16x32_bf16(af, whi[kc], acc, 0, 0, 0); \
      acc = __builtin_amdgcn_mfma_f32_16x16x32_bf16(af, wlo[kc], acc, 0, 0, 0); \
    } \
    _Pragma("unroll") \
    for (int p = 0; p < 4; ++p) hpre[4*fo + p][c0] = tanh_fast(acc[p] + bval); \
  } while(0)

#define LN_CORE() \
    f32x4 h4 = *(const f32x4*)h4p; \
    float s1 = (h4[0]+h4[1]) + (h4[2]+h4[3]); \
    float s2 = h4[0]*h4[0]; \
    s2 = fmaf(h4[1],h4[1],s2); s2 = fmaf(h4[2],h4[2],s2); s2 = fmaf(h4[3],h4[3],s2); \
    s1 = ror_add<ROR1>(s1); s1 = ror_add<ROR2>(s1); s1 = ror_add<ROR4>(s1); s1 = ror_add<ROR8>(s1); \
    s2 = ror_add<ROR1>(s2); s2 = ror_add<ROR2>(s2); s2 = ror_add<ROR4>(s2); s2 = ror_add<ROR8>(s2); \
    float S1 = (lane_f(s1,0) + lane_f(s1,16)) + (lane_f(s1,32) + lane_f(s1,48)); \
    float S2 = (lane_f(s2,0) + lane_f(s2,16)) + (lane_f(s2,32) + lane_f(s2,48)); \
    float mu  = S1 * 0.00390625f; \
    float var = S2 * 0.00390625f - mu*mu; \
    float rs  = rsq_fast(var + 1e-5f); \
    float hv0 = fmaf(h4[0]-mu, rs*g4[0], b4[0]); \
    float hv1 = fmaf(h4[1]-mu, rs*g4[1], b4[1]); \
    float hv2 = fmaf(h4[2]-mu, rs*g4[2], b4[2]); \
    float hv3 = fmaf(h4[3]-mu, rs*g4[3], b4[3]);

#define PHASE3(HW, CUSE, CLOAD, tt) do { \
    LN_CORE(); \
    if ((HW) && use_hist) { \
      uint2 hb = { pk_bf16(hv0,hv1), pk_bf16(hv2,hv3) }; \
      *(uint2*)(hist + (size_t)(tt)*(BT*H) + histLane) = hb; \
    } \
    int xv = xr[(tt)+1]; \
    f32x4 e4 = *(const f32x4*)&emb[xv][4*l]; \
    float a0, a1, a2, a3; \
    if ((CUSE) && use_hist) { \
      a0 = fmaf(cs, __uint_as_float(cP.x << 16),        e4[0] + hv0); \
      a1 = fmaf(cs, __uint_as_float(cP.x & 0xffff0000u), e4[1] + hv1); \
      a2 = fmaf(cs, __uint_as_float(cP.y << 16),        e4[2] + hv2); \
      a3 = fmaf(cs, __uint_as_float(cP.y & 0xffff0000u), e4[3] + hv3); \
    } else { \
      a0 = e4[0] + hv0; a1 = e4[1] + hv1; a2 = e4[2] + hv2; a3 = e4[3] + hv3; \
    } \
    uint2 pkk = { pk_bf16(a0,a1), pk_bf16(a2,a3) }; \
    *(uint2*)aw = pkk; \
    if ((CUSE) || (CLOAD)) { cP = cQ; } \
    if ((CLOAD) && use_hist) \
      cQ = *(const uint2*)(hist + (size_t)((tt)-61)*(BT*H) + histLane); \
  } while(0)

  // segmented t-loop: all step-uniform branches resolved at compile time per segment
  for (int t = 0; t < 61; ++t)  { PHASE2(); bar_lgkm(); PHASE3(1,0,0,t); bar_lgkm(); }
  for (int t = 61; t < 63; ++t) { PHASE2(); bar_lgkm(); PHASE3(1,0,1,t); bar_lgkm(); }
  {                               PHASE2(); bar_lgkm(); PHASE3(1,1,1,63); bar_lgkm(); }
  for (int t = 64; t < 125; ++t){ PHASE2(); bar_lgkm(); PHASE3(0,1,1,t); bar_lgkm(); }
  for (int t = 125; t < 127; ++t){PHASE2(); bar_lgkm(); PHASE3(0,1,0,t); bar_lgkm(); }
  {                               // t = 127: final LN -> f32 row
    PHASE2(); bar_lgkm();
    LN_CORE();
    f32x4 o = {hv0, hv1, hv2, hv3};
    *(f32x4*)ffin = o;
  }

  __syncthreads();
  // final projection: out = h @ W_out + b_out  ([16,256]@[256,10] per block)
  if (tid < ROWS * 10) {
    int r = tid / 10, c = tid % 10;
    float acc = bo[c];
    for (int k = 0; k < H; ++k) acc += hpre[r][k] * Wo[k*10 + c];
    out[((size_t)(r0 + r))*10 + c] = acc;
  }
}

extern "C" void kernel_launch(void* const* d_in, const int* in_sizes, int n_in,
                              void* d_out, int out_size, void* d_ws, size_t ws_size,
                              hipStream_t stream) {
  const float* x   = (const float*)d_in[0];
  const float* We  = (const float*)d_in[1];
  const float* be  = (const float*)d_in[2];
  const float* Wu  = (const float*)d_in[3];
  const float* bu  = (const float*)d_in[4];
  const float* gm  = (const float*)d_in[5];
  const float* bt  = (const float*)d_in[6];
  const float* Wo  = (const float*)d_in[7];
  const float* bo  = (const float*)d_in[8];
  const float* cst = (const float*)d_in[9];
  float* out = (float*)d_out;

  size_t need = (size_t)64 * BT * H * sizeof(unsigned short); // 128 MB history ring
  int use_hist = (ws_size >= need) ? 1 : 0;

  hipLaunchKernelGGL(wp_kernel, dim3(NBLK), dim3(NTH), 0, stream,
                     x, We, be, Wu, bu, gm, bt, Wo, bo, cst,
                     (unsigned short*)d_ws, out, use_hist);
}